// Round 8
// baseline (66.236 us; speedup 1.0000x reference)
//
#include <hip/hip_runtime.h>
#include <hip/hip_cooperative_groups.h>
#include <math.h>

namespace cg = cooperative_groups;

// Problem: B=256, D=512, H=512.
// Separable head: pre[i,j,h] = A'[j,h] + C[i,h]
//   A'[j,h] = emb[j,:] @ W1[0:512, h] + b1[h]
//   C [i,h] = emb[i,:] @ W1[512:1024, h]
// loss[i,j] = BCE(labels[i]==labels[j], sigmoid(sum_h relu(A'+C)*w2[h] + b2))
//
// Round-8: ONE cooperative kernel (256 blocks = 1/CU), grid.sync() between
// phases. Rationale: every 2-3 kernel variant lands at 34-37us while the
// arithmetic says <12us of work -> dispatch/serialization overhead dominates.
// Phase A: full-K head per block (wave d-split + LDS reduce, b1 folded).
// Phase C: proven r2 pair kernel with XOR-swizzled LDS (fits 64KB static).

#define B 256
#define D 512
#define H 512

__device__ __forceinline__ float4 fma4(float s, float4 w, float4 a) {
    a.x = fmaf(s, w.x, a.x);
    a.y = fmaf(s, w.y, a.y);
    a.z = fmaf(s, w.z, a.z);
    a.w = fmaf(s, w.w, a.w);
    return a;
}
__device__ __forceinline__ float4 add4(float4 a, float4 b) {
    a.x += b.x; a.y += b.y; a.z += b.z; a.w += b.w; return a;
}

union SharedU {
    struct {                       // ---- phase A: 32 KB
        float  sE[8 * D];          // 16 KB: 8 emb rows
        float4 part[4][8][32];     // 16 KB: [q][row][c] cross-wave partials
    } a;
    struct {                       // ---- phase C: 64 KB
        float4 sA[16][128];        // XOR-swizzled: [r][c4 ^ (r&7)]
        float4 sC[16][128];
    } c;
};

__global__ __launch_bounds__(256) void fused_product_loss(
    const float* __restrict__ emb, const int* __restrict__ labels,
    const float* __restrict__ W1, const float* __restrict__ b1,
    const float* __restrict__ w2, const float* __restrict__ b2,
    float* __restrict__ AC, float* __restrict__ out) {
    __shared__ SharedU sh;
    const int t   = threadIdx.x;
    const int bid = blockIdx.x;

    // ================= Phase A: AC[z][row][h] =================
    {
        const int z  = bid >> 7;        // 0: A', 1: C
        const int rg = (bid >> 2) & 31; // row-group of 8
        const int hq = bid & 3;         // h-quarter of 128
        const int r0 = rg * 8;
        const int h0 = hq * 128;

        // Stage 8 emb rows (contiguous 16 KB), 4 float4 per thread.
        float4* sE4 = (float4*)sh.a.sE;
        const float4* emb4 = (const float4*)(emb + (size_t)r0 * D);
#pragma unroll
        for (int i = 0; i < 4; ++i) sE4[t + 256 * i] = emb4[t + 256 * i];
        __syncthreads();

        const int c  = t & 31;          // f4-col within h-quarter
        const int q  = (t >> 5) & 3;    // d-quarter (128 d)
        const int rh = t >> 7;          // row-half (4 rows)

        float4 acc[4];
        if (z == 0 && q == 0) {         // b1 added exactly once (q==0)
            const float4 bv = *(const float4*)&b1[h0 + 4 * c];
            acc[0] = bv; acc[1] = bv; acc[2] = bv; acc[3] = bv;
        } else {
            const float4 zf = make_float4(0.f, 0.f, 0.f, 0.f);
            acc[0] = zf; acc[1] = zf; acc[2] = zf; acc[3] = zf;
        }

        const float* wp = W1 + (size_t)(z * D + q * 128) * H + h0 + 4 * c;
        const float* eb = sh.a.sE + (rh * 4) * D + q * 128;

        for (int d = 0; d < 128; d += 8) {
            float4 w[8];
#pragma unroll
            for (int k = 0; k < 8; ++k)
                w[k] = *(const float4*)(wp + (size_t)(d + k) * H);
#pragma unroll
            for (int r = 0; r < 4; ++r) {
                const float4 e0 = *(const float4*)(eb + r * D + d);
                const float4 e1 = *(const float4*)(eb + r * D + d + 4);
                acc[r] = fma4(e0.x, w[0], acc[r]);
                acc[r] = fma4(e0.y, w[1], acc[r]);
                acc[r] = fma4(e0.z, w[2], acc[r]);
                acc[r] = fma4(e0.w, w[3], acc[r]);
                acc[r] = fma4(e1.x, w[4], acc[r]);
                acc[r] = fma4(e1.y, w[5], acc[r]);
                acc[r] = fma4(e1.z, w[6], acc[r]);
                acc[r] = fma4(e1.w, w[7], acc[r]);
            }
        }

        // Cross-wave d-reduction through LDS (part[] disjoint from sE).
#pragma unroll
        for (int r = 0; r < 4; ++r) sh.a.part[q][rh * 4 + r][c] = acc[r];
        __syncthreads();

        const int rr = t >> 5;          // 0..7
        const int cc = t & 31;
        float4 s = add4(add4(sh.a.part[0][rr][cc], sh.a.part[1][rr][cc]),
                        add4(sh.a.part[2][rr][cc], sh.a.part[3][rr][cc]));
        *(float4*)&AC[(size_t)(z * B + r0 + rr) * H + h0 + 4 * cc] = s;
    }

    cg::this_grid().sync();

    // ================= Phase C: pairwise relu-dot + BCE =================
    {
        const int j0 = (bid & 15) * 16;
        const int i0 = (bid >> 4) * 16;
        const float4* Am4 = (const float4*)AC;                     // A' rows
        const float4* Cm4 = (const float4*)(AC + (size_t)B * H);   // C rows

        // Stage both 16-row tiles, XOR-swizzled, all 256 threads.
        for (int idx = t; idx < 16 * 128; idx += 256) {
            const int r  = idx >> 7;
            const int c4 = idx & 127;
            sh.c.sA[r][c4 ^ (r & 7)] = Am4[(size_t)(j0 + r) * 128 + c4];
            sh.c.sC[r][c4 ^ (r & 7)] = Cm4[(size_t)(i0 + r) * 128 + c4];
        }
        __syncthreads();

        if (t < 128) {
            const int tx = t & 15;     // j within tile
            const int ty = t >> 4;     // i rows ty and ty+8
            const int sa = tx & 7;
            const int sc = ty & 7;     // == (ty+8)&7

            float s0 = 0.0f, s1 = 0.0f;
#pragma unroll 4
            for (int h4 = 0; h4 < 128; ++h4) {
                float4 a  = sh.c.sA[tx][h4 ^ sa];
                float4 c0 = sh.c.sC[ty][h4 ^ sc];
                float4 c1 = sh.c.sC[ty + 8][h4 ^ sc];
                float4 w  = *(const float4*)&w2[4 * h4];  // uniform -> s_load
                s0 = fmaf(fmaxf(a.x + c0.x, 0.0f), w.x, s0);
                s0 = fmaf(fmaxf(a.y + c0.y, 0.0f), w.y, s0);
                s0 = fmaf(fmaxf(a.z + c0.z, 0.0f), w.z, s0);
                s0 = fmaf(fmaxf(a.w + c0.w, 0.0f), w.w, s0);
                s1 = fmaf(fmaxf(a.x + c1.x, 0.0f), w.x, s1);
                s1 = fmaf(fmaxf(a.y + c1.y, 0.0f), w.y, s1);
                s1 = fmaf(fmaxf(a.z + c1.z, 0.0f), w.z, s1);
                s1 = fmaf(fmaxf(a.w + c1.w, 0.0f), w.w, s1);
            }

            const float bias = b2[0];
            const int j  = j0 + tx;
            const int lj = labels[j];
#pragma unroll
            for (int p2 = 0; p2 < 2; ++p2) {
                const int i = i0 + ty + p2 * 8;
                const float zz = (p2 ? s1 : s0) + bias;
                float p = 1.0f / (1.0f + expf(-zz));
                p = fminf(fmaxf(p, 1e-7f), 1.0f - 1e-7f);
                const float tt = (labels[i] == lj) ? 1.0f : 0.0f;
                const float loss = -(tt * logf(p) + (1.0f - tt) * log1pf(-p));
                out[(size_t)i * B + j] = loss;
            }
        }
    }
}

extern "C" void kernel_launch(void* const* d_in, const int* in_sizes, int n_in,
                              void* d_out, int out_size, void* d_ws, size_t ws_size,
                              hipStream_t stream) {
    const float* emb    = (const float*)d_in[0];
    const int*   labels = (const int*)d_in[1];
    const float* W1     = (const float*)d_in[2];
    const float* b1     = (const float*)d_in[3];
    const float* W2     = (const float*)d_in[4];
    const float* b2     = (const float*)d_in[5];
    float* out = (float*)d_out;
    float* AC  = (float*)d_ws;   // 2*B*H floats = 1 MiB intermediate

    void* args[] = {(void*)&emb, (void*)&labels, (void*)&W1, (void*)&b1,
                    (void*)&W2, (void*)&b2, (void*)&AC, (void*)&out};
    hipLaunchCooperativeKernel((const void*)fused_product_loss,
                               dim3(256), dim3(256), args, 0, stream);
}

// Round 9
// 34.071 us; speedup vs baseline: 1.9441x; 1.9441x over previous
//
#include <hip/hip_runtime.h>
#include <math.h>

// Problem: B=256, D=512, H=512.
// Separable head: pre[i,j,h] = A'[j,h] + C[i,h]
//   A'[j,h] = emb[j,:] @ W1[0:512, h] + b1[h]
//   C [i,h] = emb[i,:] @ W1[512:1024, h]
// loss[i,j] = BCE(labels[i]==labels[j], sigmoid(sum_h relu(A'+C)*w2[h] + b2))
//
// Round-9: revert to the proven-best structure (r3 bench: 33.9us = KS=4 head
// at 512 blocks + pair_loss with inline 4-partial staging sum), with ONE
// change: W1 loads are float4 (lane owns h-f4), cutting VMEM issues 4x.
// r8 lesson: coop-fusion regressed (grid.sync + W1 re-read); launch count
// is not the bottleneck. Totals pin at ~34us across structures -> fixed
// floor suspected; this round confirms or denies it.

#define B 256
#define D 512
#define H 512
#define KS 4
#define DC (D / KS)       // 128 d-values per chunk
#define ROWS_H (B * H)    // floats per (z,ks) chunk

__device__ __forceinline__ float4 fma4(float s, float4 w, float4 a) {
    a.x = fmaf(s, w.x, a.x);
    a.y = fmaf(s, w.y, a.y);
    a.z = fmaf(s, w.z, a.z);
    a.w = fmaf(s, w.w, a.w);
    return a;
}

// ---------------- Kernel 1: partial GEMM -----------------------------------
// grid (2*KS, 32, 2) = 512 blocks, 256 threads (4 waves).
// Block: 8 rows x 256 h (colhalf) x 128 d (ks). Wave owns 2 rows; lane owns
// one h-float4 (h = colhalf*256 + 4*lane). One broadcast e-read (b128) feeds
// 16 FMAs; W1 loads are coalesced 1KB-per-wave dwordx4.
__global__ __launch_bounds__(256) void head_partial(
    const float* __restrict__ emb, const float* __restrict__ W1,
    const float* __restrict__ b1, float* __restrict__ P) {
    __shared__ float sE[8 * DC];   // 8 rows x 128 d = 4 KiB

    const int colhalf = blockIdx.x & 1;
    const int ks      = blockIdx.x >> 1;
    const int r0      = blockIdx.y * 8;
    const int z       = blockIdx.z;
    const int d0      = ks * DC;

    // Stage 8 rows x 128 d: one float4 per thread, coalesced.
    {
        const int r  = threadIdx.x >> 5;        // 0..7
        const int c4 = threadIdx.x & 31;        // 0..31
        *(float4*)&sE[r * DC + c4 * 4] =
            *(const float4*)&emb[(size_t)(r0 + r) * D + d0 + c4 * 4];
    }
    __syncthreads();

    const int wave = threadIdx.x >> 6;
    const int lane = threadIdx.x & 63;
    const int h    = colhalf * 256 + 4 * lane;  // this lane's h-float4

    float4 acc[2];
    if (z == 0 && ks == 0) {
        const float4 bv = *(const float4*)&b1[h];
        acc[0] = bv; acc[1] = bv;
    } else {
        acc[0] = make_float4(0.f, 0.f, 0.f, 0.f);
        acc[1] = acc[0];
    }

    const float* wp = W1 + (size_t)(z * D + d0) * H + h;
    const float* eb = sE + (2 * wave) * DC;     // this wave's 2 rows

#pragma unroll 4
    for (int d = 0; d < DC; d += 4) {
        float4 wv[4];
#pragma unroll
        for (int dd = 0; dd < 4; ++dd)
            wv[dd] = *(const float4*)(wp + (size_t)(d + dd) * H);  // 1KB/wave
#pragma unroll
        for (int r = 0; r < 2; ++r) {
            const float4 e = *(const float4*)&eb[r * DC + d];      // broadcast
            acc[r] = fma4(e.x, wv[0], acc[r]);
            acc[r] = fma4(e.y, wv[1], acc[r]);
            acc[r] = fma4(e.z, wv[2], acc[r]);
            acc[r] = fma4(e.w, wv[3], acc[r]);
        }
    }

    // Compact chunk layout: P[(z*KS + ks)*ROWS_H + row*H + h]
    float* chunk = P + (size_t)(z * KS + ks) * ROWS_H;
#pragma unroll
    for (int r = 0; r < 2; ++r)
        *(float4*)&chunk[(size_t)(r0 + 2 * wave + r) * H + h] = acc[r];
}

// ---------------- Kernel 2: partial-sum staging + pairwise relu-dot + BCE --
// 16x16 pair tile, 128 threads, 2 outputs/thread (proven r2/r3 structure).
#define PADH 516  // row-start bank = 4*r mod 32 -> only 2-way aliasing (free)

__global__ __launch_bounds__(128) void pair_loss(
    const float* __restrict__ P, const float* __restrict__ w2,
    const float* __restrict__ b2, const int* __restrict__ labels,
    float* __restrict__ out) {
    __shared__ float sA[16][PADH];
    __shared__ float sC[16][PADH];

    const int j0 = blockIdx.x * 16;
    const int i0 = blockIdx.y * 16;
    const int tid = threadIdx.x;
    const size_t CSTR = (size_t)ROWS_H;            // floats per chunk

    for (int idx = tid; idx < 16 * (H / 4); idx += 128) {
        const int r = idx >> 7;          // H/4 = 128 float4 per row
        const int c4 = idx & 127;
        const float* pa = P + (size_t)(j0 + r) * H + c4 * 4;               // z=0
        const float* pc = P + KS * CSTR + (size_t)(i0 + r) * H + c4 * 4;   // z=1
        float4 a0 = *(const float4*)(pa);
        float4 a1 = *(const float4*)(pa + CSTR);
        float4 a2 = *(const float4*)(pa + 2 * CSTR);
        float4 a3 = *(const float4*)(pa + 3 * CSTR);
        float4 c0 = *(const float4*)(pc);
        float4 c1 = *(const float4*)(pc + CSTR);
        float4 c2 = *(const float4*)(pc + 2 * CSTR);
        float4 c3 = *(const float4*)(pc + 3 * CSTR);
        float4 va, vc;
        va.x = (a0.x + a1.x) + (a2.x + a3.x);
        va.y = (a0.y + a1.y) + (a2.y + a3.y);
        va.z = (a0.z + a1.z) + (a2.z + a3.z);
        va.w = (a0.w + a1.w) + (a2.w + a3.w);
        vc.x = (c0.x + c1.x) + (c2.x + c3.x);
        vc.y = (c0.y + c1.y) + (c2.y + c3.y);
        vc.z = (c0.z + c1.z) + (c2.z + c3.z);
        vc.w = (c0.w + c1.w) + (c2.w + c3.w);
        *(float4*)&sA[r][c4 * 4] = va;
        *(float4*)&sC[r][c4 * 4] = vc;
    }
    __syncthreads();

    const int tx = tid & 15;   // j within tile
    const int ty = tid >> 4;   // i within tile: rows ty and ty+8

    float s0 = 0.0f, s1 = 0.0f;
#pragma unroll 4
    for (int h = 0; h < H; h += 4) {
        float4 a  = *(const float4*)&sA[tx][h];
        float4 c0 = *(const float4*)&sC[ty][h];
        float4 c1 = *(const float4*)&sC[ty + 8][h];
        float4 w  = *(const float4*)&w2[h];   // wave-uniform -> s_load
        s0 = fmaf(fmaxf(a.x + c0.x, 0.0f), w.x, s0);
        s0 = fmaf(fmaxf(a.y + c0.y, 0.0f), w.y, s0);
        s0 = fmaf(fmaxf(a.z + c0.z, 0.0f), w.z, s0);
        s0 = fmaf(fmaxf(a.w + c0.w, 0.0f), w.w, s0);
        s1 = fmaf(fmaxf(a.x + c1.x, 0.0f), w.x, s1);
        s1 = fmaf(fmaxf(a.y + c1.y, 0.0f), w.y, s1);
        s1 = fmaf(fmaxf(a.z + c1.z, 0.0f), w.z, s1);
        s1 = fmaf(fmaxf(a.w + c1.w, 0.0f), w.w, s1);
    }

    const float bias = b2[0];
    const int j = j0 + tx;
    const int lj = labels[j];

#pragma unroll
    for (int q = 0; q < 2; ++q) {
        const int i = i0 + ty + q * 8;
        const float z = (q ? s1 : s0) + bias;
        float p = 1.0f / (1.0f + expf(-z));
        p = fminf(fmaxf(p, 1e-7f), 1.0f - 1e-7f);
        const float t = (labels[i] == lj) ? 1.0f : 0.0f;
        const float loss = -(t * logf(p) + (1.0f - t) * log1pf(-p));
        out[(size_t)i * B + j] = loss;
    }
}

extern "C" void kernel_launch(void* const* d_in, const int* in_sizes, int n_in,
                              void* d_out, int out_size, void* d_ws, size_t ws_size,
                              hipStream_t stream) {
    const float* emb    = (const float*)d_in[0];
    const int*   labels = (const int*)d_in[1];
    const float* W1     = (const float*)d_in[2];
    const float* b1     = (const float*)d_in[3];
    const float* W2     = (const float*)d_in[4];
    const float* b2     = (const float*)d_in[5];
    float* out = (float*)d_out;

    float* P = (float*)d_ws;   // 2*KS*ROWS_H floats = 4 MiB of partials

    dim3 g1(2 * KS, 32, 2);
    head_partial<<<g1, 256, 0, stream>>>(emb, W1, b1, P);

    dim3 g2(16, 16);
    pair_loss<<<g2, 128, 0, stream>>>(P, W2, b2, labels, out);
}